// Round 1
// baseline (327.683 us; speedup 1.0000x reference)
//
#include <hip/hip_runtime.h>

#define SN 5
#define BB 2048
#define KK 128
#define DD 64
#define H1 256
#define H2 128

// ws layout (floats): std_w1[32768] | std_w2[32768] | std_w3[128] | std_b1[256] | std_b2[128] | std_b3[1]
#define OFF_W1 0
#define OFF_W2 32768
#define OFF_W3 65536
#define OFF_B1 65664
#define OFF_B2 65920
#define OFF_B3 66048
#define N_STD  66049

#define COMP(v,c) ((c)==0?(v).x:((c)==1?(v).y:((c)==2?(v).z:(v).w)))

__device__ __forceinline__ float sp_(float x) {
  return (x > 20.f) ? x : log1pf(__expf(x));
}
__device__ __forceinline__ float sig_(float x) { return 1.f / (1.f + __expf(-x)); }

__global__ __launch_bounds__(256) void prep_kl(
    const float* w_mu1, const float* eta_w1, const float* b_mu1, const float* eta_b1,
    const float* w_mu2, const float* eta_w2, const float* b_mu2, const float* eta_b2,
    const float* w_mu3, const float* eta_w3, const float* b_mu3, const float* eta_b3,
    float* stds, float* kl_out)
{
  int f = blockIdx.x * 256 + threadIdx.x;
  float kle = 0.f;
  const float* mu = nullptr; const float* eta = nullptr; float* so = nullptr; int off = 0;
  if      (f < 32768) { mu = w_mu1; eta = eta_w1; so = stds + OFF_W1; off = f; }
  else if (f < 65536) { mu = w_mu2; eta = eta_w2; so = stds + OFF_W2; off = f - 32768; }
  else if (f < 65664) { mu = w_mu3; eta = eta_w3; so = stds + OFF_W3; off = f - 65536; }
  else if (f < 65920) { mu = b_mu1; eta = eta_b1; so = stds + OFF_B1; off = f - 65664; }
  else if (f < 66048) { mu = b_mu2; eta = eta_b2; so = stds + OFF_B2; off = f - 65920; }
  else if (f < 66049) { mu = b_mu3; eta = eta_b3; so = stds + OFF_B3; off = 0; }
  if (mu) {
    float s = 1e-6f + sp_(eta[off]);
    so[off] = s;
    float m = mu[off];
    kle = -logf(s) + 0.5f * (s * s + m * m - 1.0f);
  }
  __shared__ float red[256];
  red[threadIdx.x] = kle;
  __syncthreads();
  for (int w = 128; w > 0; w >>= 1) {
    if (threadIdx.x < w) red[threadIdx.x] += red[threadIdx.x + w];
    __syncthreads();
  }
  if (threadIdx.x == 0) atomicAdd(kl_out, red[0]);
}

__global__ __launch_bounds__(256) void bayes_main(
    const int* __restrict__ stu_id, const int* __restrict__ exer_id,
    const float* __restrict__ kn_r,
    const float* __restrict__ stu_cnt, const float* __restrict__ exer_cnt,
    const float* __restrict__ s_emb, const float* __restrict__ e_emb,
    const float* __restrict__ k_emb,
    const float* __restrict__ e_disc_mean, const float* __restrict__ e_disc_eta,
    const float* __restrict__ w_sm, const float* __restrict__ b_sm,
    const float* __restrict__ w_ss, const float* __restrict__ b_ss,
    const float* __restrict__ w_km, const float* __restrict__ b_km,
    const float* __restrict__ w_ks, const float* __restrict__ b_ks,
    const float* __restrict__ lam1s, const float* __restrict__ lam2s,
    const float* __restrict__ lam1e, const float* __restrict__ lam2e,
    const float* __restrict__ w_mu1, const float* __restrict__ b_mu1,
    const float* __restrict__ w_mu2, const float* __restrict__ b_mu2,
    const float* __restrict__ w_mu3, const float* __restrict__ b_mu3,
    const float* __restrict__ eps_stat, const float* __restrict__ eps_kdiff,
    const float* __restrict__ eps_disc,
    const float* __restrict__ eps_w1, const float* __restrict__ eps_b1,
    const float* __restrict__ eps_w2, const float* __restrict__ eps_b2,
    const float* __restrict__ eps_w3, const float* __restrict__ eps_b3,
    const float* __restrict__ stds,
    float* __restrict__ out)
{
  const int b = blockIdx.x;
  const int t = threadIdx.x;

  __shared__ float su[DD], ee[DD];
  __shared__ float wsm[DD], wss[DD], wkm[DD], wks[DD];
  __shared__ float smean[KK], sstd[KK], kmean[KK], kstd[KK];
  __shared__ float discs[8];
  __shared__ float xs[SN][KK];
  __shared__ float h1s[SN][H1];
  __shared__ float h2s[SN][H2];

  const int stu = stu_id[b], ex = exer_id[b];

  if (t < DD) {
    su[t] = s_emb[(size_t)stu * DD + t];
    wsm[t] = w_sm[t]; wss[t] = w_ss[t];
  } else if (t < 2 * DD) {
    int d = t - DD;
    ee[d] = e_emb[(size_t)ex * DD + d];
    wkm[d] = w_km[d]; wks[d] = w_ks[d];
  }
  if (t < SN) {
    float de = sp_(e_disc_eta[ex]);
    discs[t] = sig_(e_disc_mean[ex] + de * eps_disc[(size_t)t * BB + b]);
  }
  __syncthreads();

  // phase 1: per-k stat/kdiff mean & std
  if (t < KK) {
    const int k = t;
    float am = 0.f, as = 0.f;
    const float* kr = k_emb + (size_t)k * DD;
    #pragma unroll 8
    for (int d = 0; d < DD; ++d) { float p = su[d] * kr[d]; am += p * wsm[d]; as += p * wss[d]; }
    float sdata = sp_(lam1s[0]) * __expf(-sp_(lam2s[0]) * stu_cnt[stu]);
    smean[k] = am + b_sm[0];
    sstd[k]  = sdata + sp_(as + b_ss[0]);
  } else {
    const int k = t - KK;
    float am = 0.f, as = 0.f;
    const float* kr = k_emb + (size_t)k * DD;
    #pragma unroll 8
    for (int d = 0; d < DD; ++d) { float p = ee[d] * kr[d]; am += p * wkm[d]; as += p * wks[d]; }
    float edata = sp_(lam1e[0]) * __expf(-sp_(lam2e[0]) * exer_cnt[ex]);
    kmean[k] = am + b_km[0];
    kstd[k]  = edata + sp_(as + b_ks[0]);
  }
  __syncthreads();

  // phase 2: x[s][k]
  if (t < KK) {
    const int k = t;
    float knr = kn_r[(size_t)b * KK + k];
    float sm = smean[k], ss = sstd[k], km = kmean[k], ks = kstd[k];
    #pragma unroll
    for (int s = 0; s < SN; ++s) {
      float es = eps_stat [((size_t)s * BB + b) * KK + k];
      float ek = eps_kdiff[((size_t)s * BB + b) * KK + k];
      float st = sig_(sm + ss * es);
      float kd = sig_(km + ks * ek);
      xs[s][k] = discs[s] * (st - kd) * knr;
    }
  }
  __syncthreads();

  // phase 3: layer 1 — thread t owns output row o = t
  {
    const int o = t;
    float acc[SN] = {0.f, 0.f, 0.f, 0.f, 0.f};
    const float4* ep = (const float4*)(eps_w1 + ((size_t)b * H1 + o) * KK);
    const float4* mu = (const float4*)(w_mu1 + (size_t)o * KK);
    const float4* sd = (const float4*)(stds + OFF_W1 + (size_t)o * KK);
    for (int j = 0; j < KK / 4; ++j) {
      float4 e4 = ep[j], m4 = mu[j], s4 = sd[j];
      #pragma unroll
      for (int c = 0; c < 4; ++c) {
        float w = __expf(COMP(m4, c) + COMP(s4, c) * COMP(e4, c));
        #pragma unroll
        for (int s2 = 0; s2 < SN; ++s2) acc[s2] += w * xs[s2][j * 4 + c];
      }
    }
    float bb1 = b_mu1[o] + stds[OFF_B1 + o] * eps_b1[(size_t)b * H1 + o];
    #pragma unroll
    for (int s2 = 0; s2 < SN; ++s2) h1s[s2][o] = tanhf(acc[s2] + bb1);
  }
  __syncthreads();

  // phase 4: layer 2 — pair of threads per output row
  {
    const int o = t >> 1, half = t & 1;
    const int ibase = half * KK;
    float acc[SN] = {0.f, 0.f, 0.f, 0.f, 0.f};
    const float4* ep = (const float4*)(eps_w2 + ((size_t)b * H2 + o) * H1 + ibase);
    const float4* mu = (const float4*)(w_mu2 + (size_t)o * H1 + ibase);
    const float4* sd = (const float4*)(stds + OFF_W2 + (size_t)o * H1 + ibase);
    for (int j = 0; j < KK / 4; ++j) {
      float4 e4 = ep[j], m4 = mu[j], s4 = sd[j];
      #pragma unroll
      for (int c = 0; c < 4; ++c) {
        float w = __expf(COMP(m4, c) + COMP(s4, c) * COMP(e4, c));
        #pragma unroll
        for (int s2 = 0; s2 < SN; ++s2) acc[s2] += w * h1s[s2][ibase + j * 4 + c];
      }
    }
    #pragma unroll
    for (int s2 = 0; s2 < SN; ++s2) acc[s2] += __shfl_xor(acc[s2], 1);
    if (half == 0) {
      float bb2 = b_mu2[o] + stds[OFF_B2 + o] * eps_b2[(size_t)b * H2 + o];
      #pragma unroll
      for (int s2 = 0; s2 < SN; ++s2) h2s[s2][o] = tanhf(acc[s2] + bb2);
    }
  }
  __syncthreads();

  // phase 5: layer 3 + sigmoid, wave 0 only
  if (t < 64) {
    float w3a = __expf(w_mu3[t]      + stds[OFF_W3 + t]      * eps_w3[(size_t)b * H2 + t]);
    float w3b = __expf(w_mu3[t + 64] + stds[OFF_W3 + t + 64] * eps_w3[(size_t)b * H2 + t + 64]);
    float part[SN];
    #pragma unroll
    for (int s2 = 0; s2 < SN; ++s2) part[s2] = w3a * h2s[s2][t] + w3b * h2s[s2][t + 64];
    #pragma unroll
    for (int off = 32; off >= 1; off >>= 1) {
      #pragma unroll
      for (int s2 = 0; s2 < SN; ++s2) part[s2] += __shfl_xor(part[s2], off);
    }
    if (t == 0) {
      float bb3 = b_mu3[0] + stds[OFF_B3] * eps_b3[b];
      #pragma unroll
      for (int s2 = 0; s2 < SN; ++s2) out[(size_t)s2 * BB + b] = sig_(part[s2] + bb3);
    }
  }
}

extern "C" void kernel_launch(void* const* d_in, const int* in_sizes, int n_in,
                              void* d_out, int out_size, void* d_ws, size_t ws_size,
                              hipStream_t stream) {
  const int*   stu_id      = (const int*)  d_in[0];
  const int*   exer_id     = (const int*)  d_in[1];
  const float* kn_r        = (const float*)d_in[2];
  const float* stu_cnt     = (const float*)d_in[3];
  const float* exer_cnt    = (const float*)d_in[4];
  const float* s_emb       = (const float*)d_in[5];
  const float* e_emb       = (const float*)d_in[6];
  const float* k_emb       = (const float*)d_in[7];
  const float* e_disc_mean = (const float*)d_in[8];
  const float* e_disc_eta  = (const float*)d_in[9];
  const float* w_sm        = (const float*)d_in[10];
  const float* b_sm        = (const float*)d_in[11];
  const float* w_ss        = (const float*)d_in[12];
  const float* b_ss        = (const float*)d_in[13];
  const float* w_km        = (const float*)d_in[14];
  const float* b_km        = (const float*)d_in[15];
  const float* w_ks        = (const float*)d_in[16];
  const float* b_ks        = (const float*)d_in[17];
  const float* lam1s       = (const float*)d_in[18];
  const float* lam2s       = (const float*)d_in[19];
  const float* lam1e       = (const float*)d_in[20];
  const float* lam2e       = (const float*)d_in[21];
  const float* w_mu1       = (const float*)d_in[22];
  const float* eta_w1      = (const float*)d_in[23];
  const float* b_mu1       = (const float*)d_in[24];
  const float* eta_b1      = (const float*)d_in[25];
  const float* w_mu2       = (const float*)d_in[26];
  const float* eta_w2      = (const float*)d_in[27];
  const float* b_mu2       = (const float*)d_in[28];
  const float* eta_b2      = (const float*)d_in[29];
  const float* w_mu3       = (const float*)d_in[30];
  const float* eta_w3      = (const float*)d_in[31];
  const float* b_mu3       = (const float*)d_in[32];
  const float* eta_b3      = (const float*)d_in[33];
  const float* eps_stat    = (const float*)d_in[34];
  const float* eps_kdiff   = (const float*)d_in[35];
  const float* eps_disc    = (const float*)d_in[36];
  const float* eps_w1      = (const float*)d_in[37];
  const float* eps_b1      = (const float*)d_in[38];
  const float* eps_w2      = (const float*)d_in[39];
  const float* eps_b2      = (const float*)d_in[40];
  const float* eps_w3      = (const float*)d_in[41];
  const float* eps_b3      = (const float*)d_in[42];

  float* out  = (float*)d_out;
  float* stds = (float*)d_ws;

  // zero the KL slot (out[10240]); graph-capture-safe
  hipMemsetAsync((char*)d_out + (size_t)SN * BB * sizeof(float), 0, sizeof(float), stream);

  prep_kl<<<(N_STD + 255) / 256, 256, 0, stream>>>(
      w_mu1, eta_w1, b_mu1, eta_b1,
      w_mu2, eta_w2, b_mu2, eta_b2,
      w_mu3, eta_w3, b_mu3, eta_b3,
      stds, out + (size_t)SN * BB);

  bayes_main<<<BB, 256, 0, stream>>>(
      stu_id, exer_id, kn_r, stu_cnt, exer_cnt,
      s_emb, e_emb, k_emb, e_disc_mean, e_disc_eta,
      w_sm, b_sm, w_ss, b_ss, w_km, b_km, w_ks, b_ks,
      lam1s, lam2s, lam1e, lam2e,
      w_mu1, b_mu1, w_mu2, b_mu2, w_mu3, b_mu3,
      eps_stat, eps_kdiff, eps_disc,
      eps_w1, eps_b1, eps_w2, eps_b2, eps_w3, eps_b3,
      stds, out);
}

// Round 2
// 174.692 us; speedup vs baseline: 1.8758x; 1.8758x over previous
//
#include <hip/hip_runtime.h>

#define SN 5
#define BB 2048
#define KK 128
#define DD 64
#define H1 256
#define H2 128

// ws layout (floats): std_w1[32768] | std_w2[32768] | std_w3[128] | std_b1[256] | std_b2[128] | std_b3[1]
#define OFF_W1 0
#define OFF_W2 32768
#define OFF_W3 65536
#define OFF_B1 65664
#define OFF_B2 65920
#define OFF_B3 66048
#define N_STD  66049

__device__ __forceinline__ float sp_(float x) {
  return (x > 20.f) ? x : log1pf(__expf(x));
}
__device__ __forceinline__ float sig_(float x) { return 1.f / (1.f + __expf(-x)); }

__global__ __launch_bounds__(256) void prep_kl(
    const float* w_mu1, const float* eta_w1, const float* b_mu1, const float* eta_b1,
    const float* w_mu2, const float* eta_w2, const float* b_mu2, const float* eta_b2,
    const float* w_mu3, const float* eta_w3, const float* b_mu3, const float* eta_b3,
    float* stds, float* kl_out)
{
  int f = blockIdx.x * 256 + threadIdx.x;
  float kle = 0.f;
  const float* mu = nullptr; const float* eta = nullptr; float* so = nullptr; int off = 0;
  if      (f < 32768) { mu = w_mu1; eta = eta_w1; so = stds + OFF_W1; off = f; }
  else if (f < 65536) { mu = w_mu2; eta = eta_w2; so = stds + OFF_W2; off = f - 32768; }
  else if (f < 65664) { mu = w_mu3; eta = eta_w3; so = stds + OFF_W3; off = f - 65536; }
  else if (f < 65920) { mu = b_mu1; eta = eta_b1; so = stds + OFF_B1; off = f - 65664; }
  else if (f < 66048) { mu = b_mu2; eta = eta_b2; so = stds + OFF_B2; off = f - 65920; }
  else if (f < 66049) { mu = b_mu3; eta = eta_b3; so = stds + OFF_B3; off = 0; }
  if (mu) {
    float s = 1e-6f + sp_(eta[off]);
    so[off] = s;
    float m = mu[off];
    kle = -logf(s) + 0.5f * (s * s + m * m - 1.0f);
  }
  __shared__ float red[256];
  red[threadIdx.x] = kle;
  __syncthreads();
  for (int w = 128; w > 0; w >>= 1) {
    if (threadIdx.x < w) red[threadIdx.x] += red[threadIdx.x + w];
    __syncthreads();
  }
  if (threadIdx.x == 0) atomicAdd(kl_out, red[0]);
}

__global__ __launch_bounds__(256, 4) void bayes_main(
    const int* __restrict__ stu_id, const int* __restrict__ exer_id,
    const float* __restrict__ kn_r,
    const float* __restrict__ stu_cnt, const float* __restrict__ exer_cnt,
    const float* __restrict__ s_emb, const float* __restrict__ e_emb,
    const float* __restrict__ k_emb,
    const float* __restrict__ e_disc_mean, const float* __restrict__ e_disc_eta,
    const float* __restrict__ w_sm, const float* __restrict__ b_sm,
    const float* __restrict__ w_ss, const float* __restrict__ b_ss,
    const float* __restrict__ w_km, const float* __restrict__ b_km,
    const float* __restrict__ w_ks, const float* __restrict__ b_ks,
    const float* __restrict__ lam1s, const float* __restrict__ lam2s,
    const float* __restrict__ lam1e, const float* __restrict__ lam2e,
    const float* __restrict__ w_mu1, const float* __restrict__ b_mu1,
    const float* __restrict__ w_mu2, const float* __restrict__ b_mu2,
    const float* __restrict__ w_mu3, const float* __restrict__ b_mu3,
    const float* __restrict__ eps_stat, const float* __restrict__ eps_kdiff,
    const float* __restrict__ eps_disc,
    const float* __restrict__ eps_w1, const float* __restrict__ eps_b1,
    const float* __restrict__ eps_w2, const float* __restrict__ eps_b2,
    const float* __restrict__ eps_w3, const float* __restrict__ eps_b3,
    const float* __restrict__ stds,
    float* __restrict__ out)
{
  const int b = blockIdx.x;
  const int t = threadIdx.x;

  __shared__ float su[DD], ee[DD];
  __shared__ float wsm[DD], wss[DD], wkm[DD], wks[DD];
  __shared__ float smean[KK], sstd[KK], kmean[KK], kstd[KK];
  __shared__ float discs[8];
  __shared__ __align__(16) float xs[SN][KK];
  __shared__ __align__(16) float h1s[SN][H1];
  __shared__ __align__(16) float h2s[SN][H2];
  __shared__ float bias1[H1];
  __shared__ float bias2[H2];
  __shared__ float w3v[H2];

  const int stu = stu_id[b], ex = exer_id[b];

  // ---- phase 0: small gathers + per-b bias/w3 precompute (coalesced) ----
  if (t < DD) {
    su[t] = s_emb[(size_t)stu * DD + t];
    wsm[t] = w_sm[t]; wss[t] = w_ss[t];
  } else if (t < 2 * DD) {
    int d = t - DD;
    ee[d] = e_emb[(size_t)ex * DD + d];
    wkm[d] = w_km[d]; wks[d] = w_ks[d];
  }
  bias1[t] = b_mu1[t] + stds[OFF_B1 + t] * eps_b1[(size_t)b * H1 + t];
  if (t < H2) {
    bias2[t] = b_mu2[t] + stds[OFF_B2 + t] * eps_b2[(size_t)b * H2 + t];
    w3v[t] = __expf(w_mu3[t] + stds[OFF_W3 + t] * eps_w3[(size_t)b * H2 + t]);
  }
  if (t < SN) {
    float de = sp_(e_disc_eta[ex]);
    discs[t] = sig_(e_disc_mean[ex] + de * eps_disc[(size_t)t * BB + b]);
  }
  __syncthreads();

  // ---- phase 1: per-k stat/kdiff mean & std ----
  if (t < KK) {
    const int k = t;
    float am = 0.f, as = 0.f;
    const float* kr = k_emb + (size_t)k * DD;
    #pragma unroll 8
    for (int d = 0; d < DD; ++d) { float p = su[d] * kr[d]; am += p * wsm[d]; as += p * wss[d]; }
    float sdata = sp_(lam1s[0]) * __expf(-sp_(lam2s[0]) * stu_cnt[stu]);
    smean[k] = am + b_sm[0];
    sstd[k]  = sdata + sp_(as + b_ss[0]);
  } else {
    const int k = t - KK;
    float am = 0.f, as = 0.f;
    const float* kr = k_emb + (size_t)k * DD;
    #pragma unroll 8
    for (int d = 0; d < DD; ++d) { float p = ee[d] * kr[d]; am += p * wkm[d]; as += p * wks[d]; }
    float edata = sp_(lam1e[0]) * __expf(-sp_(lam2e[0]) * exer_cnt[ex]);
    kmean[k] = am + b_km[0];
    kstd[k]  = edata + sp_(as + b_ks[0]);
  }
  __syncthreads();

  // ---- phase 2: x[s][k] ----
  if (t < KK) {
    const int k = t;
    float knr = kn_r[(size_t)b * KK + k];
    float sm = smean[k], ss = sstd[k], km = kmean[k], ks = kstd[k];
    #pragma unroll
    for (int s = 0; s < SN; ++s) {
      float es = eps_stat [((size_t)s * BB + b) * KK + k];
      float ek = eps_kdiff[((size_t)s * BB + b) * KK + k];
      float st = sig_(sm + ss * es);
      float kd = sig_(km + ks * ek);
      xs[s][k] = discs[s] * (st - kd) * knr;
    }
  }
  __syncthreads();

  const int g = t >> 4, l16 = t & 15;

  // ---- phase 3: layer 1 — 16 lanes per output row, coalesced, eps prefetch ----
  {
    const float4* epb = (const float4*)(eps_w1 + (size_t)b * H1 * KK); // row stride 32 f4
    const float4* mub = (const float4*)w_mu1;
    const float4* sdb = (const float4*)(stds + OFF_W1);
    float4 e0 = epb[(size_t)g * 32 + l16];
    float4 e1 = epb[(size_t)g * 32 + 16 + l16];
    for (int p = 0; p < 16; ++p) {
      const int o = p * 16 + g;
      const int on = (p < 15) ? o + 16 : o;
      float4 ne0 = epb[(size_t)on * 32 + l16];
      float4 ne1 = epb[(size_t)on * 32 + 16 + l16];
      float4 m0 = mub[(size_t)o * 32 + l16];
      float4 m1 = mub[(size_t)o * 32 + 16 + l16];
      float4 s0 = sdb[(size_t)o * 32 + l16];
      float4 s1 = sdb[(size_t)o * 32 + 16 + l16];
      float w0 = __expf(m0.x + s0.x * e0.x);
      float w1 = __expf(m0.y + s0.y * e0.y);
      float w2 = __expf(m0.z + s0.z * e0.z);
      float w3 = __expf(m0.w + s0.w * e0.w);
      float w4 = __expf(m1.x + s1.x * e1.x);
      float w5 = __expf(m1.y + s1.y * e1.y);
      float w6 = __expf(m1.z + s1.z * e1.z);
      float w7 = __expf(m1.w + s1.w * e1.w);
      float acc[SN];
      #pragma unroll
      for (int s2 = 0; s2 < SN; ++s2) {
        float4 xa = *(const float4*)&xs[s2][l16 * 4];
        float4 xb = *(const float4*)&xs[s2][64 + l16 * 4];
        acc[s2] = w0 * xa.x + w1 * xa.y + w2 * xa.z + w3 * xa.w
                + w4 * xb.x + w5 * xb.y + w6 * xb.z + w7 * xb.w;
      }
      #pragma unroll
      for (int mk = 1; mk <= 8; mk <<= 1) {
        #pragma unroll
        for (int s2 = 0; s2 < SN; ++s2) acc[s2] += __shfl_xor(acc[s2], mk);
      }
      if (l16 == 0) {
        #pragma unroll
        for (int s2 = 0; s2 < SN; ++s2) h1s[s2][o] = tanhf(acc[s2] + bias1[o]);
      }
      e0 = ne0; e1 = ne1;
    }
  }
  __syncthreads();

  // ---- phase 4: layer 2 — 16 lanes per output row (256 inputs) ----
  {
    const float4* epb = (const float4*)(eps_w2 + (size_t)b * H2 * H1); // row stride 64 f4
    const float4* mub = (const float4*)w_mu2;
    const float4* sdb = (const float4*)(stds + OFF_W2);
    float4 e0 = epb[(size_t)g * 64 + l16];
    float4 e1 = epb[(size_t)g * 64 + 16 + l16];
    float4 e2 = epb[(size_t)g * 64 + 32 + l16];
    float4 e3 = epb[(size_t)g * 64 + 48 + l16];
    for (int p = 0; p < 8; ++p) {
      const int o = p * 16 + g;
      const int on = (p < 7) ? o + 16 : o;
      float4 ne0 = epb[(size_t)on * 64 + l16];
      float4 ne1 = epb[(size_t)on * 64 + 16 + l16];
      float4 ne2 = epb[(size_t)on * 64 + 32 + l16];
      float4 ne3 = epb[(size_t)on * 64 + 48 + l16];
      float4 m0 = mub[(size_t)o * 64 + l16];
      float4 m1 = mub[(size_t)o * 64 + 16 + l16];
      float4 m2 = mub[(size_t)o * 64 + 32 + l16];
      float4 m3 = mub[(size_t)o * 64 + 48 + l16];
      float4 s0 = sdb[(size_t)o * 64 + l16];
      float4 s1 = sdb[(size_t)o * 64 + 16 + l16];
      float4 s2v = sdb[(size_t)o * 64 + 32 + l16];
      float4 s3 = sdb[(size_t)o * 64 + 48 + l16];
      float wa0 = __expf(m0.x + s0.x * e0.x);
      float wa1 = __expf(m0.y + s0.y * e0.y);
      float wa2 = __expf(m0.z + s0.z * e0.z);
      float wa3 = __expf(m0.w + s0.w * e0.w);
      float wb0 = __expf(m1.x + s1.x * e1.x);
      float wb1 = __expf(m1.y + s1.y * e1.y);
      float wb2 = __expf(m1.z + s1.z * e1.z);
      float wb3 = __expf(m1.w + s1.w * e1.w);
      float wc0 = __expf(m2.x + s2v.x * e2.x);
      float wc1 = __expf(m2.y + s2v.y * e2.y);
      float wc2 = __expf(m2.z + s2v.z * e2.z);
      float wc3 = __expf(m2.w + s2v.w * e2.w);
      float wd0 = __expf(m3.x + s3.x * e3.x);
      float wd1 = __expf(m3.y + s3.y * e3.y);
      float wd2 = __expf(m3.z + s3.z * e3.z);
      float wd3 = __expf(m3.w + s3.w * e3.w);
      float acc[SN];
      #pragma unroll
      for (int s2 = 0; s2 < SN; ++s2) {
        float4 xa = *(const float4*)&h1s[s2][l16 * 4];
        float4 xb = *(const float4*)&h1s[s2][64 + l16 * 4];
        float4 xc = *(const float4*)&h1s[s2][128 + l16 * 4];
        float4 xd = *(const float4*)&h1s[s2][192 + l16 * 4];
        acc[s2] = wa0 * xa.x + wa1 * xa.y + wa2 * xa.z + wa3 * xa.w
                + wb0 * xb.x + wb1 * xb.y + wb2 * xb.z + wb3 * xb.w
                + wc0 * xc.x + wc1 * xc.y + wc2 * xc.z + wc3 * xc.w
                + wd0 * xd.x + wd1 * xd.y + wd2 * xd.z + wd3 * xd.w;
      }
      #pragma unroll
      for (int mk = 1; mk <= 8; mk <<= 1) {
        #pragma unroll
        for (int s2 = 0; s2 < SN; ++s2) acc[s2] += __shfl_xor(acc[s2], mk);
      }
      if (l16 == 0) {
        #pragma unroll
        for (int s2 = 0; s2 < SN; ++s2) h2s[s2][o] = tanhf(acc[s2] + bias2[o]);
      }
      e0 = ne0; e1 = ne1; e2 = ne2; e3 = ne3;
    }
  }
  __syncthreads();

  // ---- phase 5: layer 3 + sigmoid, wave 0 only ----
  if (t < 64) {
    float w3a = w3v[t];
    float w3b = w3v[t + 64];
    float part[SN];
    #pragma unroll
    for (int s2 = 0; s2 < SN; ++s2) part[s2] = w3a * h2s[s2][t] + w3b * h2s[s2][t + 64];
    #pragma unroll
    for (int off = 32; off >= 1; off >>= 1) {
      #pragma unroll
      for (int s2 = 0; s2 < SN; ++s2) part[s2] += __shfl_xor(part[s2], off);
    }
    if (t == 0) {
      float bb3 = b_mu3[0] + stds[OFF_B3] * eps_b3[b];
      #pragma unroll
      for (int s2 = 0; s2 < SN; ++s2) out[(size_t)s2 * BB + b] = sig_(part[s2] + bb3);
    }
  }
}

extern "C" void kernel_launch(void* const* d_in, const int* in_sizes, int n_in,
                              void* d_out, int out_size, void* d_ws, size_t ws_size,
                              hipStream_t stream) {
  const int*   stu_id      = (const int*)  d_in[0];
  const int*   exer_id     = (const int*)  d_in[1];
  const float* kn_r        = (const float*)d_in[2];
  const float* stu_cnt     = (const float*)d_in[3];
  const float* exer_cnt    = (const float*)d_in[4];
  const float* s_emb       = (const float*)d_in[5];
  const float* e_emb       = (const float*)d_in[6];
  const float* k_emb       = (const float*)d_in[7];
  const float* e_disc_mean = (const float*)d_in[8];
  const float* e_disc_eta  = (const float*)d_in[9];
  const float* w_sm        = (const float*)d_in[10];
  const float* b_sm        = (const float*)d_in[11];
  const float* w_ss        = (const float*)d_in[12];
  const float* b_ss        = (const float*)d_in[13];
  const float* w_km        = (const float*)d_in[14];
  const float* b_km        = (const float*)d_in[15];
  const float* w_ks        = (const float*)d_in[16];
  const float* b_ks        = (const float*)d_in[17];
  const float* lam1s       = (const float*)d_in[18];
  const float* lam2s       = (const float*)d_in[19];
  const float* lam1e       = (const float*)d_in[20];
  const float* lam2e       = (const float*)d_in[21];
  const float* w_mu1       = (const float*)d_in[22];
  const float* eta_w1      = (const float*)d_in[23];
  const float* b_mu1       = (const float*)d_in[24];
  const float* eta_b1      = (const float*)d_in[25];
  const float* w_mu2       = (const float*)d_in[26];
  const float* eta_w2      = (const float*)d_in[27];
  const float* b_mu2       = (const float*)d_in[28];
  const float* eta_b2      = (const float*)d_in[29];
  const float* w_mu3       = (const float*)d_in[30];
  const float* eta_w3      = (const float*)d_in[31];
  const float* b_mu3       = (const float*)d_in[32];
  const float* eta_b3      = (const float*)d_in[33];
  const float* eps_stat    = (const float*)d_in[34];
  const float* eps_kdiff   = (const float*)d_in[35];
  const float* eps_disc    = (const float*)d_in[36];
  const float* eps_w1      = (const float*)d_in[37];
  const float* eps_b1      = (const float*)d_in[38];
  const float* eps_w2      = (const float*)d_in[39];
  const float* eps_b2      = (const float*)d_in[40];
  const float* eps_w3      = (const float*)d_in[41];
  const float* eps_b3      = (const float*)d_in[42];

  float* out  = (float*)d_out;
  float* stds = (float*)d_ws;

  hipMemsetAsync((char*)d_out + (size_t)SN * BB * sizeof(float), 0, sizeof(float), stream);

  prep_kl<<<(N_STD + 255) / 256, 256, 0, stream>>>(
      w_mu1, eta_w1, b_mu1, eta_b1,
      w_mu2, eta_w2, b_mu2, eta_b2,
      w_mu3, eta_w3, b_mu3, eta_b3,
      stds, out + (size_t)SN * BB);

  bayes_main<<<BB, 256, 0, stream>>>(
      stu_id, exer_id, kn_r, stu_cnt, exer_cnt,
      s_emb, e_emb, k_emb, e_disc_mean, e_disc_eta,
      w_sm, b_sm, w_ss, b_ss, w_km, b_km, w_ks, b_ks,
      lam1s, lam2s, lam1e, lam2e,
      w_mu1, b_mu1, w_mu2, b_mu2, w_mu3, b_mu3,
      eps_stat, eps_kdiff, eps_disc,
      eps_w1, eps_b1, eps_w2, eps_b2, eps_w3, eps_b3,
      stds, out);
}

// Round 4
// 161.261 us; speedup vs baseline: 2.0320x; 1.0833x over previous
//
#include <hip/hip_runtime.h>

#define SN 5
#define BB 2048
#define KK 128
#define DD 64
#define H1 256
#define H2 128

// ws layout (floats): std_w1[32768] | std_w2[32768] | std_w3[128] | std_b1[256] | std_b2[128] | std_b3[1]
#define OFF_W1 0
#define OFF_W2 32768
#define OFF_W3 65536
#define OFF_B1 65664
#define OFF_B2 65920
#define OFF_B3 66048
#define N_STD  66049

__device__ __forceinline__ float sp_(float x) {
  return (x > 20.f) ? x : log1pf(__expf(x));
}
__device__ __forceinline__ float sig_(float x) { return 1.f / (1.f + __expf(-x)); }

__device__ __forceinline__ float4 exp4_(float4 m, float4 s, float4 e) {
  float4 r;
  r.x = __expf(m.x + s.x * e.x);
  r.y = __expf(m.y + s.y * e.y);
  r.z = __expf(m.z + s.z * e.z);
  r.w = __expf(m.w + s.w * e.w);
  return r;
}
__device__ __forceinline__ float dot4_(float4 a, float4 b) {
  return a.x * b.x + a.y * b.y + a.z * b.z + a.w * b.w;
}

__global__ __launch_bounds__(256) void prep_kl(
    const float* w_mu1, const float* eta_w1, const float* b_mu1, const float* eta_b1,
    const float* w_mu2, const float* eta_w2, const float* b_mu2, const float* eta_b2,
    const float* w_mu3, const float* eta_w3, const float* b_mu3, const float* eta_b3,
    float* stds, float* kl_out)
{
  int f = blockIdx.x * 256 + threadIdx.x;
  float kle = 0.f;
  const float* mu = nullptr; const float* eta = nullptr; float* so = nullptr; int off = 0;
  if      (f < 32768) { mu = w_mu1; eta = eta_w1; so = stds + OFF_W1; off = f; }
  else if (f < 65536) { mu = w_mu2; eta = eta_w2; so = stds + OFF_W2; off = f - 32768; }
  else if (f < 65664) { mu = w_mu3; eta = eta_w3; so = stds + OFF_W3; off = f - 65536; }
  else if (f < 65920) { mu = b_mu1; eta = eta_b1; so = stds + OFF_B1; off = f - 65664; }
  else if (f < 66048) { mu = b_mu2; eta = eta_b2; so = stds + OFF_B2; off = f - 65920; }
  else if (f < 66049) { mu = b_mu3; eta = eta_b3; so = stds + OFF_B3; off = 0; }
  if (mu) {
    float s = 1e-6f + sp_(eta[off]);
    so[off] = s;
    float m = mu[off];
    kle = -logf(s) + 0.5f * (s * s + m * m - 1.0f);
  }
  __shared__ float red[256];
  red[threadIdx.x] = kle;
  __syncthreads();
  for (int w = 128; w > 0; w >>= 1) {
    if (threadIdx.x < w) red[threadIdx.x] += red[threadIdx.x + w];
    __syncthreads();
  }
  if (threadIdx.x == 0) atomicAdd(kl_out, red[0]);
}

__global__ __launch_bounds__(256, 4) void bayes_main(
    const int* __restrict__ stu_id, const int* __restrict__ exer_id,
    const float* __restrict__ kn_r,
    const float* __restrict__ stu_cnt, const float* __restrict__ exer_cnt,
    const float* __restrict__ s_emb, const float* __restrict__ e_emb,
    const float* __restrict__ k_emb,
    const float* __restrict__ e_disc_mean, const float* __restrict__ e_disc_eta,
    const float* __restrict__ w_sm, const float* __restrict__ b_sm,
    const float* __restrict__ w_ss, const float* __restrict__ b_ss,
    const float* __restrict__ w_km, const float* __restrict__ b_km,
    const float* __restrict__ w_ks, const float* __restrict__ b_ks,
    const float* __restrict__ lam1s, const float* __restrict__ lam2s,
    const float* __restrict__ lam1e, const float* __restrict__ lam2e,
    const float* __restrict__ w_mu1, const float* __restrict__ b_mu1,
    const float* __restrict__ w_mu2, const float* __restrict__ b_mu2,
    const float* __restrict__ w_mu3, const float* __restrict__ b_mu3,
    const float* __restrict__ eps_stat, const float* __restrict__ eps_kdiff,
    const float* __restrict__ eps_disc,
    const float* __restrict__ eps_w1, const float* __restrict__ eps_b1,
    const float* __restrict__ eps_w2, const float* __restrict__ eps_b2,
    const float* __restrict__ eps_w3, const float* __restrict__ eps_b3,
    const float* __restrict__ stds,
    float* __restrict__ out)
{
  const int b = blockIdx.x;
  const int t = threadIdx.x;

  __shared__ float su[DD], ee[DD];
  __shared__ float wsm[DD], wss[DD], wkm[DD], wks[DD];
  __shared__ float smean[KK], sstd[KK], kmean[KK], kstd[KK];
  __shared__ float discs[8];
  __shared__ __align__(16) float xs[SN][KK];
  __shared__ __align__(16) float h1s[SN][H1];
  __shared__ __align__(16) float h2s[SN][H2];
  __shared__ float bias1[H1];
  __shared__ float bias2[H2];
  __shared__ float w3v[H2];

  const int stu = stu_id[b], ex = exer_id[b];

  // ---- phase 0: small gathers + per-b bias/w3 precompute ----
  if (t < DD) {
    su[t] = s_emb[(size_t)stu * DD + t];
    wsm[t] = w_sm[t]; wss[t] = w_ss[t];
  } else if (t < 2 * DD) {
    int d = t - DD;
    ee[d] = e_emb[(size_t)ex * DD + d];
    wkm[d] = w_km[d]; wks[d] = w_ks[d];
  }
  bias1[t] = b_mu1[t] + stds[OFF_B1 + t] * eps_b1[(size_t)b * H1 + t];
  if (t < H2) {
    bias2[t] = b_mu2[t] + stds[OFF_B2 + t] * eps_b2[(size_t)b * H2 + t];
    w3v[t] = __expf(w_mu3[t] + stds[OFF_W3 + t] * eps_w3[(size_t)b * H2 + t]);
  }
  if (t < SN) {
    float de = sp_(e_disc_eta[ex]);
    discs[t] = sig_(e_disc_mean[ex] + de * eps_disc[(size_t)t * BB + b]);
  }
  __syncthreads();

  // ---- phase 1: per-k stat/kdiff mean & std ----
  if (t < KK) {
    const int k = t;
    float am = 0.f, as = 0.f;
    const float* kr = k_emb + (size_t)k * DD;
    #pragma unroll 8
    for (int d = 0; d < DD; ++d) { float p = su[d] * kr[d]; am += p * wsm[d]; as += p * wss[d]; }
    float sdata = sp_(lam1s[0]) * __expf(-sp_(lam2s[0]) * stu_cnt[stu]);
    smean[k] = am + b_sm[0];
    sstd[k]  = sdata + sp_(as + b_ss[0]);
  } else {
    const int k = t - KK;
    float am = 0.f, as = 0.f;
    const float* kr = k_emb + (size_t)k * DD;
    #pragma unroll 8
    for (int d = 0; d < DD; ++d) { float p = ee[d] * kr[d]; am += p * wkm[d]; as += p * wks[d]; }
    float edata = sp_(lam1e[0]) * __expf(-sp_(lam2e[0]) * exer_cnt[ex]);
    kmean[k] = am + b_km[0];
    kstd[k]  = edata + sp_(as + b_ks[0]);
  }
  __syncthreads();

  // ---- phase 2: x[s][k] ----
  if (t < KK) {
    const int k = t;
    float knr = kn_r[(size_t)b * KK + k];
    float sm = smean[k], ss = sstd[k], km = kmean[k], ks = kstd[k];
    #pragma unroll
    for (int s = 0; s < SN; ++s) {
      float es = eps_stat [((size_t)s * BB + b) * KK + k];
      float ek = eps_kdiff[((size_t)s * BB + b) * KK + k];
      float st = sig_(sm + ss * es);
      float kd = sig_(km + ks * ek);
      xs[s][k] = discs[s] * (st - kd) * knr;
    }
  }
  __syncthreads();

  const int g = t >> 4, l16 = t & 15;

  // ---- phase 3: layer 1 — 2 rows per group per pass, paired-exchange reduce ----
  {
    const int lane1 = g * 32 + l16;  // f4 units
    const float4* ep = (const float4*)(eps_w1 + (size_t)b * H1 * KK) + lane1;
    const float4* mp = (const float4*)w_mu1 + lane1;
    const float4* sq = (const float4*)(stds + OFF_W1) + lane1;

    float4 eA0 = ep[0], eA1 = ep[16], eA2 = ep[512], eA3 = ep[528];
    float4 eB0, eB1, eB2, eB3;

    #pragma unroll
    for (int p = 0; p < 8; ++p) {
      const int B0 = p * 1024;
      float4 ce0, ce1, ce2, ce3;
      if (p & 1) { ce0 = eB0; ce1 = eB1; ce2 = eB2; ce3 = eB3; }
      else       { ce0 = eA0; ce1 = eA1; ce2 = eA2; ce3 = eA3; }
      if (p < 7) {
        if (p & 1) {
          eA0 = ep[B0 + 1024]; eA1 = ep[B0 + 1040];
          eA2 = ep[B0 + 1536]; eA3 = ep[B0 + 1552];
        } else {
          eB0 = ep[B0 + 1024]; eB1 = ep[B0 + 1040];
          eB2 = ep[B0 + 1536]; eB3 = ep[B0 + 1552];
        }
      }
      float4 m0 = mp[B0], m1 = mp[B0 + 16], m2 = mp[B0 + 512], m3 = mp[B0 + 528];
      float4 s0 = sq[B0], s1 = sq[B0 + 16], s2v = sq[B0 + 512], s3 = sq[B0 + 528];
      float4 wA0 = exp4_(m0, s0, ce0);
      float4 wA1 = exp4_(m1, s1, ce1);
      float4 wB0 = exp4_(m2, s2v, ce2);
      float4 wB1 = exp4_(m3, s3, ce3);

      float red[SN];
      #pragma unroll
      for (int s2 = 0; s2 < SN; ++s2) {
        float4 xa = *(const float4*)&xs[s2][l16 * 4];
        float4 xb = *(const float4*)&xs[s2][64 + l16 * 4];
        float a0 = dot4_(wA0, xa) + dot4_(wA1, xb);
        float a1 = dot4_(wB0, xa) + dot4_(wB1, xb);
        float u0 = __shfl_xor(a0, 8);
        float u1 = __shfl_xor(a1, 8);
        float a = (l16 < 8) ? (a0 + u0) : (a1 + u1);
        a += __shfl_xor(a, 4);
        a += __shfl_xor(a, 2);
        a += __shfl_xor(a, 1);
        red[s2] = a;
      }
      const int o0 = p * 32 + g, o1 = o0 + 16;
      if (l16 == 0) {
        #pragma unroll
        for (int s2 = 0; s2 < SN; ++s2) h1s[s2][o0] = tanhf(red[s2] + bias1[o0]);
      } else if (l16 == 8) {
        #pragma unroll
        for (int s2 = 0; s2 < SN; ++s2) h1s[s2][o1] = tanhf(red[s2] + bias1[o1]);
      }
    }
  }
  __syncthreads();

  // ---- phase 4: layer 2 — 2 rows per group per pass ----
  {
    const int lane2 = g * 64 + l16;  // f4 units
    const float4* ep = (const float4*)(eps_w2 + (size_t)b * H2 * H1) + lane2;
    const float4* mp = (const float4*)w_mu2 + lane2;
    const float4* sq = (const float4*)(stds + OFF_W2) + lane2;

    float4 fA[8], fB[8];
    #pragma unroll
    for (int c = 0; c < 4; ++c) {
      fA[c]     = ep[c * 16];
      fA[4 + c] = ep[1024 + c * 16];
    }

    #pragma unroll
    for (int p = 0; p < 4; ++p) {
      const int B0 = p * 2048;
      float4 cf[8];
      #pragma unroll
      for (int c = 0; c < 8; ++c) cf[c] = (p & 1) ? fB[c] : fA[c];
      if (p < 3) {
        #pragma unroll
        for (int c = 0; c < 4; ++c) {
          if (p & 1) {
            fA[c]     = ep[B0 + 2048 + c * 16];
            fA[4 + c] = ep[B0 + 3072 + c * 16];
          } else {
            fB[c]     = ep[B0 + 2048 + c * 16];
            fB[4 + c] = ep[B0 + 3072 + c * 16];
          }
        }
      }
      float a0[SN] = {0.f, 0.f, 0.f, 0.f, 0.f};
      float a1[SN] = {0.f, 0.f, 0.f, 0.f, 0.f};
      #pragma unroll
      for (int c = 0; c < 4; ++c) {
        float4 m0 = mp[B0 + c * 16], s0 = sq[B0 + c * 16];
        float4 m1 = mp[B0 + 1024 + c * 16], s1 = sq[B0 + 1024 + c * 16];
        float4 w0 = exp4_(m0, s0, cf[c]);
        float4 w1 = exp4_(m1, s1, cf[4 + c]);
        #pragma unroll
        for (int s2 = 0; s2 < SN; ++s2) {
          float4 h = *(const float4*)&h1s[s2][c * 64 + l16 * 4];
          a0[s2] += dot4_(w0, h);
          a1[s2] += dot4_(w1, h);
        }
      }
      float red[SN];
      #pragma unroll
      for (int s2 = 0; s2 < SN; ++s2) {
        float u0 = __shfl_xor(a0[s2], 8);
        float u1 = __shfl_xor(a1[s2], 8);
        float a = (l16 < 8) ? (a0[s2] + u0) : (a1[s2] + u1);
        a += __shfl_xor(a, 4);
        a += __shfl_xor(a, 2);
        a += __shfl_xor(a, 1);
        red[s2] = a;
      }
      const int o0 = p * 32 + g, o1 = o0 + 16;
      if (l16 == 0) {
        #pragma unroll
        for (int s2 = 0; s2 < SN; ++s2) h2s[s2][o0] = tanhf(red[s2] + bias2[o0]);
      } else if (l16 == 8) {
        #pragma unroll
        for (int s2 = 0; s2 < SN; ++s2) h2s[s2][o1] = tanhf(red[s2] + bias2[o1]);
      }
    }
  }
  __syncthreads();

  // ---- phase 5: layer 3 + sigmoid, wave 0 only ----
  if (t < 64) {
    float w3a = w3v[t];
    float w3b = w3v[t + 64];
    float part[SN];
    #pragma unroll
    for (int s2 = 0; s2 < SN; ++s2) part[s2] = w3a * h2s[s2][t] + w3b * h2s[s2][t + 64];
    #pragma unroll
    for (int off = 32; off >= 1; off >>= 1) {
      #pragma unroll
      for (int s2 = 0; s2 < SN; ++s2) part[s2] += __shfl_xor(part[s2], off);
    }
    if (t == 0) {
      float bb3 = b_mu3[0] + stds[OFF_B3] * eps_b3[b];
      #pragma unroll
      for (int s2 = 0; s2 < SN; ++s2) out[(size_t)s2 * BB + b] = sig_(part[s2] + bb3);
    }
  }
}

extern "C" void kernel_launch(void* const* d_in, const int* in_sizes, int n_in,
                              void* d_out, int out_size, void* d_ws, size_t ws_size,
                              hipStream_t stream) {
  const int*   stu_id      = (const int*)  d_in[0];
  const int*   exer_id     = (const int*)  d_in[1];
  const float* kn_r        = (const float*)d_in[2];
  const float* stu_cnt     = (const float*)d_in[3];
  const float* exer_cnt    = (const float*)d_in[4];
  const float* s_emb       = (const float*)d_in[5];
  const float* e_emb       = (const float*)d_in[6];
  const float* k_emb       = (const float*)d_in[7];
  const float* e_disc_mean = (const float*)d_in[8];
  const float* e_disc_eta  = (const float*)d_in[9];
  const float* w_sm        = (const float*)d_in[10];
  const float* b_sm        = (const float*)d_in[11];
  const float* w_ss        = (const float*)d_in[12];
  const float* b_ss        = (const float*)d_in[13];
  const float* w_km        = (const float*)d_in[14];
  const float* b_km        = (const float*)d_in[15];
  const float* w_ks        = (const float*)d_in[16];
  const float* b_ks        = (const float*)d_in[17];
  const float* lam1s       = (const float*)d_in[18];
  const float* lam2s       = (const float*)d_in[19];
  const float* lam1e       = (const float*)d_in[20];
  const float* lam2e       = (const float*)d_in[21];
  const float* w_mu1       = (const float*)d_in[22];
  const float* eta_w1      = (const float*)d_in[23];
  const float* b_mu1       = (const float*)d_in[24];
  const float* eta_b1      = (const float*)d_in[25];
  const float* w_mu2       = (const float*)d_in[26];
  const float* eta_w2      = (const float*)d_in[27];
  const float* b_mu2       = (const float*)d_in[28];
  const float* eta_b2      = (const float*)d_in[29];
  const float* w_mu3       = (const float*)d_in[30];
  const float* eta_w3      = (const float*)d_in[31];
  const float* b_mu3       = (const float*)d_in[32];
  const float* eta_b3      = (const float*)d_in[33];
  const float* eps_stat    = (const float*)d_in[34];
  const float* eps_kdiff   = (const float*)d_in[35];
  const float* eps_disc    = (const float*)d_in[36];
  const float* eps_w1      = (const float*)d_in[37];
  const float* eps_b1      = (const float*)d_in[38];
  const float* eps_w2      = (const float*)d_in[39];
  const float* eps_b2      = (const float*)d_in[40];
  const float* eps_w3      = (const float*)d_in[41];
  const float* eps_b3      = (const float*)d_in[42];

  float* out  = (float*)d_out;
  float* stds = (float*)d_ws;

  hipMemsetAsync((char*)d_out + (size_t)SN * BB * sizeof(float), 0, sizeof(float), stream);

  prep_kl<<<(N_STD + 255) / 256, 256, 0, stream>>>(
      w_mu1, eta_w1, b_mu1, eta_b1,
      w_mu2, eta_w2, b_mu2, eta_b2,
      w_mu3, eta_w3, b_mu3, eta_b3,
      stds, out + (size_t)SN * BB);

  bayes_main<<<BB, 256, 0, stream>>>(
      stu_id, exer_id, kn_r, stu_cnt, exer_cnt,
      s_emb, e_emb, k_emb, e_disc_mean, e_disc_eta,
      w_sm, b_sm, w_ss, b_ss, w_km, b_km, w_ks, b_ks,
      lam1s, lam2s, lam1e, lam2e,
      w_mu1, b_mu1, w_mu2, b_mu2, w_mu3, b_mu3,
      eps_stat, eps_kdiff, eps_disc,
      eps_w1, eps_b1, eps_w2, eps_b2, eps_w3, eps_b3,
      stds, out);
}